// Round 1
// baseline (450.629 us; speedup 1.0000x reference)
//
#include <hip/hip_runtime.h>
#include <stdint.h>
#include <stddef.h>

#define BATCH 32768
#define HDIM  1024
#define NFAM  10

typedef short bf16x8 __attribute__((ext_vector_type(8)));
typedef float f32x4  __attribute__((ext_vector_type(4)));

// fp32 -> bf16 round-to-nearest-even
__device__ __forceinline__ unsigned short f2bf(float x) {
  unsigned int u = __builtin_bit_cast(unsigned int, x);
  u += 0x7fffu + ((u >> 16) & 1u);
  return (unsigned short)(u >> 16);
}

// async global->LDS, 16B per lane. LDS dest must be wave-uniform base + lane*16.
__device__ __forceinline__ void async_cp16(unsigned short* lds_dst, const unsigned short* g_src) {
  __builtin_amdgcn_global_load_lds(
      (const __attribute__((address_space(1))) unsigned int*)g_src,
      (__attribute__((address_space(3))) unsigned int*)lds_dst,
      16, 0, 0);
}

// ---------------------------------------------------------------------------
// Transpose + cast: in f32 [R][C] row-major -> out bf16 [C][R]
// ---------------------------------------------------------------------------
__global__ __launch_bounds__(256) void transpose_cast(
    const float* __restrict__ in, unsigned short* __restrict__ out, int R, int C) {
  __shared__ float tile[64][65];
  const int t = threadIdx.x;
  const int c = t & 63;
  const int r0 = t >> 6;
  const int rbase = blockIdx.y * 64, cbase = blockIdx.x * 64;
#pragma unroll
  for (int i = 0; i < 16; ++i) {
    int r = r0 + i * 4;
    tile[r][c] = in[(size_t)(rbase + r) * C + cbase + c];
  }
  __syncthreads();
#pragma unroll
  for (int i = 0; i < 16; ++i) {
    int r = r0 + i * 4;
    out[(size_t)(cbase + r) * R + rbase + c] = f2bf(tile[c][r]);
  }
}

// ---------------------------------------------------------------------------
// Prototype squared norms. One block per family.
// ---------------------------------------------------------------------------
__global__ __launch_bounds__(256) void proto_prep(
    const float* __restrict__ protos, float* __restrict__ p2) {
  __shared__ float red[4];
  const int j = blockIdx.x, t = threadIdx.x;
  float4 v = ((const float4*)(protos + (size_t)j * HDIM))[t];
  float s = v.x * v.x + v.y * v.y + v.z * v.z + v.w * v.w;
#pragma unroll
  for (int o = 32; o > 0; o >>= 1) s += __shfl_down(s, o);
  if ((t & 63) == 0) red[t >> 6] = s;
  __syncthreads();
  if (t == 0) p2[j] = red[0] + red[1] + red[2] + red[3];
}

// ---------------------------------------------------------------------------
// protoC[j][n] = b1[n] + sum_k protos[j][k] * W1[H + k][n]   (exact fp32)
// Only 10 distinct prototype rows ever hit the bottom half of W1, so the
// entire proto-half of GEMM1 collapses into this 10x1024 table.
// Grid: (HDIM/256, NFAM). W reads coalesced across lanes; p reads uniform.
// ---------------------------------------------------------------------------
__global__ __launch_bounds__(256) void proto_contrib(
    const float* __restrict__ protos, const float* __restrict__ W1,
    const float* __restrict__ b1, float* __restrict__ protoC) {
  const int j = blockIdx.y;
  const int n = blockIdx.x * 256 + threadIdx.x;
  const float* w = W1 + (size_t)HDIM * HDIM + n;   // bottom half of W1, col n
  const float* p = protos + (size_t)j * HDIM;
  float s0 = 0.f, s1 = 0.f, s2 = 0.f, s3 = 0.f;
#pragma unroll 4
  for (int k = 0; k < HDIM; k += 4) {
    s0 += p[k]     * w[(size_t)k * HDIM];
    s1 += p[k + 1] * w[(size_t)(k + 1) * HDIM];
    s2 += p[k + 2] * w[(size_t)(k + 2) * HDIM];
    s3 += p[k + 3] * w[(size_t)(k + 3) * HDIM];
  }
  protoC[j * HDIM + n] = (s0 + s1) + (s2 + s3) + b1[n];
}

// ---------------------------------------------------------------------------
// Nearest prototype + features->bf16 cast.
// Protos cached in LDS (40 KB). 16 rows/block: 4 waves x 4 rows sequential.
// ---------------------------------------------------------------------------
__global__ __launch_bounds__(256) void nearest_kernel(
    const float* __restrict__ feats, const float* __restrict__ protos,
    const float* __restrict__ p2, unsigned short* __restrict__ featsB,
    int* __restrict__ idx) {
  __shared__ float pl[NFAM * HDIM];  // fp32 protos, 40 KB
  const int t = threadIdx.x;
#pragma unroll
  for (int j = 0; j < NFAM; ++j)
    ((float4*)pl)[t + 256 * j] = ((const float4*)protos)[t + 256 * j];
  __syncthreads();

  const int wave = t >> 6, lane = t & 63;
  float P2[NFAM];
#pragma unroll
  for (int j = 0; j < NFAM; ++j) P2[j] = p2[j];

#pragma unroll
  for (int rr = 0; rr < 4; ++rr) {
    const int row = blockIdx.x * 16 + wave * 4 + rr;
    const float* f = feats + (size_t)row * HDIM;

    float dot[NFAM];
#pragma unroll
    for (int j = 0; j < NFAM; ++j) dot[j] = 0.f;
    float f2 = 0.f;

#pragma unroll
    for (int ch = 0; ch < 4; ++ch) {
      const int k4 = ch * 64 + lane;  // float4 index within row
      float4 v = ((const float4*)f)[k4];
      f2 += v.x * v.x + v.y * v.y + v.z * v.z + v.w * v.w;
#pragma unroll
      for (int j = 0; j < NFAM; ++j) {
        float4 p = ((const float4*)pl)[j * 256 + k4];
        dot[j] += v.x * p.x + v.y * p.y + v.z * p.z + v.w * p.w;
      }
      uint2 pk;
      pk.x = (unsigned)f2bf(v.x) | ((unsigned)f2bf(v.y) << 16);
      pk.y = (unsigned)f2bf(v.z) | ((unsigned)f2bf(v.w) << 16);
      *(uint2*)(featsB + (size_t)row * HDIM + k4 * 4) = pk;
    }

#pragma unroll
    for (int o = 32; o > 0; o >>= 1) {
      f2 += __shfl_down(f2, o);
#pragma unroll
      for (int j = 0; j < NFAM; ++j) dot[j] += __shfl_down(dot[j], o);
    }
    if (lane == 0) {
      int best = 0;
      float bd = f2 + P2[0] - 2.f * dot[0];
#pragma unroll
      for (int j = 1; j < NFAM; ++j) {
        float d = f2 + P2[j] - 2.f * dot[j];
        if (d < bd) { bd = d; best = j; }
      }
      idx[row] = best;
    }
  }
}

// ---------------------------------------------------------------------------
// bf16 GEMM, K=1024 fixed. A and B staged via global_load_lds. BK=64 (two
// 32-k sub-buffers per operand). XOR source-swizzle: LDS slot (row, p) holds
// global 16B-piece p ^ ((row>>1)&3), so ds_read_b128 readers spread 16 lanes
// over all 8 four-bank slots (2-way = free, m136).
// 128x128 tile, 4 waves as 2x2 of 64x64, 16x16x32 MFMA.
// XCD swizzle: b&7 -> XCD; each XCD sweeps all 8 col-blocks of a row-panel
// so the B panel stays L2/L3-resident.
// EPI=1: out = relu(acc + protoC[idx[row]][col]) -> bf16   (protoC holds b1)
// EPI=0: out = acc + bias[col] -> f32
// ---------------------------------------------------------------------------
template <int EPI>
__global__ __launch_bounds__(256) void gemm_kernel(
    const unsigned short* __restrict__ A,   // [M][1024] bf16
    const unsigned short* __restrict__ Bt,  // [1024][1024] bf16, n-major
    const int* __restrict__ idx,            // [M]            (EPI=1)
    const float* __restrict__ protoC,       // [NFAM][1024]   (EPI=1)
    const float* __restrict__ bias,         // [1024]         (EPI=0)
    unsigned short* __restrict__ outB,      // [M][1024] bf16 (EPI=1)
    float* __restrict__ outF) {             // [M][1024] f32  (EPI=0)
  constexpr int K = 1024;
  __shared__ unsigned short ldsA[2][128 * 32];  // [sub][row*32 + piece*8]
  __shared__ unsigned short ldsB[2][128 * 32];
  __shared__ int idxLds[128];

  const int t    = threadIdx.x;
  const int lane = t & 63;
  const int wid  = t >> 6;
  const int quad = lane >> 4;
  const int r16  = lane & 15;

  // swizzled block decode: col = (b>>3)&7, row = (b>>6)*8 + (b&7)
  const int b = blockIdx.x;
  const int rowBase = ((b >> 6) * 8 + (b & 7)) * 128;
  const int colBase = ((b >> 3) & 7) * 128;
  const int wm = (wid >> 1) * 64;
  const int wn = (wid & 1) * 64;

  if (EPI) {
    if (t < 128) idxLds[t] = idx[rowBase + t];
    __syncthreads();
  }

  f32x4 acc[4][4];
#pragma unroll
  for (int i = 0; i < 4; ++i)
#pragma unroll
    for (int j = 0; j < 4; ++j) acc[i][j] = (f32x4){0.f, 0.f, 0.f, 0.f};

  // staging: thread t handles rows r0 = t>>2 and r1 = r0+64, piece p = t&3.
  // swizzled global piece q = p ^ ((row>>1)&3); identical for r0 and r1
  // since they differ by 64 (64>>1 = 32 == 0 mod 4).
  const int r0 = t >> 2, r1 = r0 + 64;
  const int q = (t & 3) ^ ((t >> 3) & 3);
  const unsigned short* aBase0 = A + (size_t)(rowBase + r0) * K + q * 8;
  const unsigned short* aBase1 = A + (size_t)(rowBase + r1) * K + q * 8;
  const unsigned short* bB0 = Bt + (size_t)(colBase + r0) * K + q * 8;
  const unsigned short* bB1 = Bt + (size_t)(colBase + r1) * K + q * 8;

  // reader piece (per-lane constant): global quad lives at LDS piece
  // quad ^ ((r16>>1)&3)  (wm/wn/mi*16 are ==0 mod 8 after >>1, mod 4)
  const int pr = quad ^ ((r16 >> 1) & 3);

  for (int kb = 0; kb < K; kb += 64) {
#pragma unroll
    for (int s = 0; s < 2; ++s) {
      async_cp16(&ldsA[s][t * 8],         aBase0 + kb + s * 32);
      async_cp16(&ldsA[s][(t + 256) * 8], aBase1 + kb + s * 32);
      async_cp16(&ldsB[s][t * 8],         bB0 + kb + s * 32);
      async_cp16(&ldsB[s][(t + 256) * 8], bB1 + kb + s * 32);
    }
    __syncthreads();

#pragma unroll
    for (int s = 0; s < 2; ++s) {
      bf16x8 af[4], bfr[4];
#pragma unroll
      for (int mi = 0; mi < 4; ++mi)
        af[mi] = *(const bf16x8*)(&ldsA[s][(wm + mi * 16 + r16) * 32 + pr * 8]);
#pragma unroll
      for (int ni = 0; ni < 4; ++ni)
        bfr[ni] = *(const bf16x8*)(&ldsB[s][(wn + ni * 16 + r16) * 32 + pr * 8]);
#pragma unroll
      for (int mi = 0; mi < 4; ++mi)
#pragma unroll
        for (int ni = 0; ni < 4; ++ni)
          acc[mi][ni] = __builtin_amdgcn_mfma_f32_16x16x32_bf16(af[mi], bfr[ni], acc[mi][ni], 0, 0, 0);
    }
    __syncthreads();
  }

  // epilogue: C/D layout col=lane&15, row=quad*4+reg  [m89/m91]
#pragma unroll
  for (int mi = 0; mi < 4; ++mi) {
    const int lrow0 = wm + mi * 16 + quad * 4;
    int pid[4];
    if (EPI) {
#pragma unroll
      for (int r = 0; r < 4; ++r) pid[r] = idxLds[lrow0 + r];
    }
#pragma unroll
    for (int ni = 0; ni < 4; ++ni) {
      const int grow0 = rowBase + lrow0;
      const int gcol  = colBase + wn + ni * 16 + r16;
      if (EPI) {
#pragma unroll
        for (int r = 0; r < 4; ++r) {
          float v = acc[mi][ni][r] + protoC[(size_t)pid[r] * HDIM + gcol];
          v = fmaxf(v, 0.0f);
          outB[(size_t)(grow0 + r) * 1024 + gcol] = f2bf(v);
        }
      } else {
        const float bv = bias[gcol];
#pragma unroll
        for (int r = 0; r < 4; ++r)
          outF[(size_t)(grow0 + r) * 1024 + gcol] = acc[mi][ni][r] + bv;
      }
    }
  }
}

// ---------------------------------------------------------------------------
// Workspace layout (~138.4 MB): featsB | hiddenB | W1t | W2t | protoC | p2 | idx
// ---------------------------------------------------------------------------
extern "C" void kernel_launch(void* const* d_in, const int* in_sizes, int n_in,
                              void* d_out, int out_size, void* d_ws, size_t ws_size,
                              hipStream_t stream) {
  const float* feats  = (const float*)d_in[0];
  const float* protos = (const float*)d_in[1];
  const float* W1     = (const float*)d_in[2];
  const float* b1     = (const float*)d_in[3];
  const float* W2     = (const float*)d_in[4];
  const float* b2     = (const float*)d_in[5];
  float* out = (float*)d_out;

  unsigned short* featsB  = (unsigned short*)d_ws;
  unsigned short* hiddenB = featsB + (size_t)BATCH * HDIM;
  unsigned short* W1t     = hiddenB + (size_t)BATCH * HDIM;   // top half only
  unsigned short* W2t     = W1t + (size_t)HDIM * HDIM;
  float* protoC = (float*)(W2t + (size_t)HDIM * HDIM);        // [NFAM][HDIM]
  float* p2     = protoC + NFAM * HDIM;
  int* idx      = (int*)(p2 + NFAM + 2);

  // W1 top half [1024][1024] -> bf16 [n][k]; W2 [1024][1024] -> bf16 [n][k]
  transpose_cast<<<dim3(HDIM / 64, HDIM / 64), 256, 0, stream>>>(W1, W1t, HDIM, HDIM);
  transpose_cast<<<dim3(HDIM / 64, HDIM / 64), 256, 0, stream>>>(W2, W2t, HDIM, HDIM);
  proto_prep<<<NFAM, 256, 0, stream>>>(protos, p2);
  proto_contrib<<<dim3(HDIM / 256, NFAM), 256, 0, stream>>>(protos, W1, b1, protoC);
  nearest_kernel<<<BATCH / 16, 256, 0, stream>>>(feats, protos, p2, featsB, idx);
  // GEMM1: hidden = relu(feats @ W1top + protoC[idx])     K=1024
  gemm_kernel<1><<<2048, 256, 0, stream>>>(featsB, W1t, idx, protoC, nullptr, hiddenB, nullptr);
  // GEMM2: out = hidden @ W2 + b2                          K=1024
  gemm_kernel<0><<<2048, 256, 0, stream>>>(hiddenB, W2t, nullptr, nullptr, b2, nullptr, out);
}

// Round 2
// 429.790 us; speedup vs baseline: 1.0485x; 1.0485x over previous
//
#include <hip/hip_runtime.h>
#include <stdint.h>
#include <stddef.h>

#define BATCH 32768
#define HDIM  1024
#define NFAM  10

typedef short bf16x8 __attribute__((ext_vector_type(8)));
typedef float f32x4  __attribute__((ext_vector_type(4)));

// fp32 -> bf16 round-to-nearest-even
__device__ __forceinline__ unsigned short f2bf(float x) {
  unsigned int u = __builtin_bit_cast(unsigned int, x);
  u += 0x7fffu + ((u >> 16) & 1u);
  return (unsigned short)(u >> 16);
}

// async global->LDS, 16B per lane. LDS dest must be wave-uniform base + lane*16.
__device__ __forceinline__ void async_cp16(unsigned short* lds_dst, const unsigned short* g_src) {
  __builtin_amdgcn_global_load_lds(
      (const __attribute__((address_space(1))) unsigned int*)g_src,
      (__attribute__((address_space(3))) unsigned int*)lds_dst,
      16, 0, 0);
}

// ---------------------------------------------------------------------------
// Transpose + cast: in f32 [R][C] row-major -> out bf16 [C][R]
// ---------------------------------------------------------------------------
__global__ __launch_bounds__(256) void transpose_cast(
    const float* __restrict__ in, unsigned short* __restrict__ out, int R, int C) {
  __shared__ float tile[64][65];
  const int t = threadIdx.x;
  const int c = t & 63;
  const int r0 = t >> 6;
  const int rbase = blockIdx.y * 64, cbase = blockIdx.x * 64;
#pragma unroll
  for (int i = 0; i < 16; ++i) {
    int r = r0 + i * 4;
    tile[r][c] = in[(size_t)(rbase + r) * C + cbase + c];
  }
  __syncthreads();
#pragma unroll
  for (int i = 0; i < 16; ++i) {
    int r = r0 + i * 4;
    out[(size_t)(cbase + r) * R + rbase + c] = f2bf(tile[c][r]);
  }
}

// ---------------------------------------------------------------------------
// Prototype squared norms. One block per family.
// ---------------------------------------------------------------------------
__global__ __launch_bounds__(256) void proto_prep(
    const float* __restrict__ protos, float* __restrict__ p2) {
  __shared__ float red[4];
  const int j = blockIdx.x, t = threadIdx.x;
  float4 v = ((const float4*)(protos + (size_t)j * HDIM))[t];
  float s = v.x * v.x + v.y * v.y + v.z * v.z + v.w * v.w;
#pragma unroll
  for (int o = 32; o > 0; o >>= 1) s += __shfl_down(s, o);
  if ((t & 63) == 0) red[t >> 6] = s;
  __syncthreads();
  if (t == 0) p2[j] = red[0] + red[1] + red[2] + red[3];
}

// ---------------------------------------------------------------------------
// protoC[j][n] = b1[n] + sum_k protos[j][k] * W1[H + k][n]   (fp32)
// Parallel over k: grid (16 n-chunks of 64, NFAM). Block = 4 waves, each wave
// owns a 256-wide k-strip (wave-uniform proto reads -> s_loads), LDS reduce.
// ---------------------------------------------------------------------------
__global__ __launch_bounds__(256) void proto_contrib(
    const float* __restrict__ protos, const float* __restrict__ W1,
    const float* __restrict__ b1, float* __restrict__ protoC) {
  __shared__ float red[4][64];
  const int j  = blockIdx.y;
  const int ln = threadIdx.x & 63;               // n within chunk
  const int ks = threadIdx.x >> 6;               // k-strip 0..3
  const int n  = blockIdx.x * 64 + ln;
  const float* p = protos + (size_t)j * HDIM + ks * 256;
  const float* w = W1 + (size_t)(HDIM + ks * 256) * HDIM + n;
  float s = 0.f;
#pragma unroll 16
  for (int kk = 0; kk < 256; ++kk)
    s += p[kk] * w[(size_t)kk * HDIM];
  red[ks][ln] = s;
  __syncthreads();
  if (ks == 0)
    protoC[j * HDIM + n] = red[0][ln] + red[1][ln] + red[2][ln] + red[3][ln] + b1[n];
}

// ---------------------------------------------------------------------------
// Nearest prototype + features->bf16 cast.
// Protos cached in LDS (40 KB). 16 rows/block: 4 waves x 4 rows sequential.
// ---------------------------------------------------------------------------
__global__ __launch_bounds__(256) void nearest_kernel(
    const float* __restrict__ feats, const float* __restrict__ protos,
    const float* __restrict__ p2, unsigned short* __restrict__ featsB,
    int* __restrict__ idx) {
  __shared__ float pl[NFAM * HDIM];  // fp32 protos, 40 KB
  const int t = threadIdx.x;
#pragma unroll
  for (int j = 0; j < NFAM; ++j)
    ((float4*)pl)[t + 256 * j] = ((const float4*)protos)[t + 256 * j];
  __syncthreads();

  const int wave = t >> 6, lane = t & 63;
  float P2[NFAM];
#pragma unroll
  for (int j = 0; j < NFAM; ++j) P2[j] = p2[j];

#pragma unroll
  for (int rr = 0; rr < 4; ++rr) {
    const int row = blockIdx.x * 16 + wave * 4 + rr;
    const float* f = feats + (size_t)row * HDIM;

    float dot[NFAM];
#pragma unroll
    for (int j = 0; j < NFAM; ++j) dot[j] = 0.f;
    float f2 = 0.f;

#pragma unroll
    for (int ch = 0; ch < 4; ++ch) {
      const int k4 = ch * 64 + lane;  // float4 index within row
      float4 v = ((const float4*)f)[k4];
      f2 += v.x * v.x + v.y * v.y + v.z * v.z + v.w * v.w;
#pragma unroll
      for (int j = 0; j < NFAM; ++j) {
        float4 p = ((const float4*)pl)[j * 256 + k4];
        dot[j] += v.x * p.x + v.y * p.y + v.z * p.z + v.w * p.w;
      }
      uint2 pk;
      pk.x = (unsigned)f2bf(v.x) | ((unsigned)f2bf(v.y) << 16);
      pk.y = (unsigned)f2bf(v.z) | ((unsigned)f2bf(v.w) << 16);
      *(uint2*)(featsB + (size_t)row * HDIM + k4 * 4) = pk;
    }

#pragma unroll
    for (int o = 32; o > 0; o >>= 1) {
      f2 += __shfl_down(f2, o);
#pragma unroll
      for (int j = 0; j < NFAM; ++j) dot[j] += __shfl_down(dot[j], o);
    }
    if (lane == 0) {
      int best = 0;
      float bd = f2 + P2[0] - 2.f * dot[0];
#pragma unroll
      for (int j = 1; j < NFAM; ++j) {
        float d = f2 + P2[j] - 2.f * dot[j];
        if (d < bd) { bd = d; best = j; }
      }
      idx[row] = best;
    }
  }
}

// ---------------------------------------------------------------------------
// bf16 GEMM, K=1024. 128x128 tile, 4 waves as 2x2 of 64x64, 16x16x32 MFMA.
// Pipelined: LDS double-buffer (64 KB, 2 blocks/CU), next tile's
// global_load_lds issued BEFORE computing current, counted s_waitcnt vmcnt(8)
// (per-wave VMEM FIFO is exactly [cur x8][next x8]), raw s_barrier (no
// compiler vmcnt(0) drain). Barrier #1: buf[cur] staged for all waves.
// Barrier #2: all waves done reading buf[cur] before t+1 overwrites it.
// XOR source-swizzle keeps ds_read_b128 conflict-free (measured 0 conflicts).
// XCD swizzle: b&7 -> XCD; each XCD sweeps all 8 col-blocks of a row-panel.
// EPI=1: out = relu(acc + protoC[idx[row]][col]) -> bf16   (protoC holds b1)
// EPI=0: out = acc + bias[col] -> f32
// ---------------------------------------------------------------------------
template <int EPI>
__global__ __launch_bounds__(256) void gemm_kernel(
    const unsigned short* __restrict__ A,   // [M][1024] bf16
    const unsigned short* __restrict__ Bt,  // [1024][1024] bf16, n-major
    const int* __restrict__ idx,            // [M]            (EPI=1)
    const float* __restrict__ protoC,       // [NFAM][1024]   (EPI=1)
    const float* __restrict__ bias,         // [1024]         (EPI=0)
    unsigned short* __restrict__ outB,      // [M][1024] bf16 (EPI=1)
    float* __restrict__ outF) {             // [M][1024] f32  (EPI=0)
  constexpr int K = 1024;
  __shared__ unsigned short ldsA[2][2][128 * 32];  // [buf][sub][row*32 + piece*8]
  __shared__ unsigned short ldsB[2][2][128 * 32];  // total 64 KB

  const int t    = threadIdx.x;
  const int lane = t & 63;
  const int wid  = t >> 6;
  const int quad = lane >> 4;
  const int r16  = lane & 15;

  // swizzled block decode: col = (b>>3)&7, row = (b>>6)*8 + (b&7)
  const int b = blockIdx.x;
  const int rowBase = ((b >> 6) * 8 + (b & 7)) * 128;
  const int colBase = ((b >> 3) & 7) * 128;
  const int wm = (wid >> 1) * 64;
  const int wn = (wid & 1) * 64;

  f32x4 acc[4][4];
#pragma unroll
  for (int i = 0; i < 4; ++i)
#pragma unroll
    for (int j = 0; j < 4; ++j) acc[i][j] = (f32x4){0.f, 0.f, 0.f, 0.f};

  // staging: thread t handles rows r0 = t>>2 and r1 = r0+64, piece p = t&3.
  // swizzled global piece q = p ^ ((row>>1)&3); identical for r0 and r1.
  const int r0 = t >> 2, r1 = r0 + 64;
  const int q = (t & 3) ^ ((t >> 3) & 3);
  const unsigned short* aBase0 = A + (size_t)(rowBase + r0) * K + q * 8;
  const unsigned short* aBase1 = A + (size_t)(rowBase + r1) * K + q * 8;
  const unsigned short* bB0 = Bt + (size_t)(colBase + r0) * K + q * 8;
  const unsigned short* bB1 = Bt + (size_t)(colBase + r1) * K + q * 8;

  // reader piece (per-lane constant)
  const int pr = quad ^ ((r16 >> 1) & 3);

#define ISSUE_TILE(buf, kb)                                        \
  {                                                                \
    _Pragma("unroll")                                              \
    for (int s = 0; s < 2; ++s) {                                  \
      async_cp16(&ldsA[buf][s][t * 8],         aBase0 + (kb) + s * 32); \
      async_cp16(&ldsA[buf][s][(t + 256) * 8], aBase1 + (kb) + s * 32); \
      async_cp16(&ldsB[buf][s][t * 8],         bB0 + (kb) + s * 32);    \
      async_cp16(&ldsB[buf][s][(t + 256) * 8], bB1 + (kb) + s * 32);    \
    }                                                              \
  }

  ISSUE_TILE(0, 0);
  int cur = 0;
  for (int kb = 0; kb < K; kb += 64) {
    if (kb + 64 < K) {
      ISSUE_TILE(cur ^ 1, kb + 64);
      asm volatile("s_waitcnt vmcnt(8)" ::: "memory");  // cur's 8 loads landed
    } else {
      asm volatile("s_waitcnt vmcnt(0)" ::: "memory");
    }
    __builtin_amdgcn_s_barrier();        // buf[cur] staged for all waves
    __builtin_amdgcn_sched_barrier(0);

#pragma unroll
    for (int s = 0; s < 2; ++s) {
      bf16x8 af[4], bfr[4];
#pragma unroll
      for (int mi = 0; mi < 4; ++mi)
        af[mi] = *(const bf16x8*)(&ldsA[cur][s][(wm + mi * 16 + r16) * 32 + pr * 8]);
#pragma unroll
      for (int ni = 0; ni < 4; ++ni)
        bfr[ni] = *(const bf16x8*)(&ldsB[cur][s][(wn + ni * 16 + r16) * 32 + pr * 8]);
#pragma unroll
      for (int mi = 0; mi < 4; ++mi)
#pragma unroll
        for (int ni = 0; ni < 4; ++ni)
          acc[mi][ni] = __builtin_amdgcn_mfma_f32_16x16x32_bf16(af[mi], bfr[ni], acc[mi][ni], 0, 0, 0);
    }

    __builtin_amdgcn_sched_barrier(0);
    __builtin_amdgcn_s_barrier();        // all waves done reading buf[cur]
    cur ^= 1;
  }
#undef ISSUE_TILE

  // epilogue: C/D layout col=lane&15, row=quad*4+reg  [m89/m91]
#pragma unroll
  for (int mi = 0; mi < 4; ++mi) {
    const int lrow0 = wm + mi * 16 + quad * 4;
    const int grow0 = rowBase + lrow0;
    int pid[4];
    if (EPI) {
#pragma unroll
      for (int r = 0; r < 4; ++r) pid[r] = idx[grow0 + r];  // L2-hot
    }
#pragma unroll
    for (int ni = 0; ni < 4; ++ni) {
      const int gcol = colBase + wn + ni * 16 + r16;
      if (EPI) {
#pragma unroll
        for (int r = 0; r < 4; ++r) {
          float v = acc[mi][ni][r] + protoC[(size_t)pid[r] * HDIM + gcol];
          v = fmaxf(v, 0.0f);
          outB[(size_t)(grow0 + r) * 1024 + gcol] = f2bf(v);
        }
      } else {
        const float bv = bias[gcol];
#pragma unroll
        for (int r = 0; r < 4; ++r)
          outF[(size_t)(grow0 + r) * 1024 + gcol] = acc[mi][ni][r] + bv;
      }
    }
  }
}

// ---------------------------------------------------------------------------
// Workspace layout (~138.4 MB): featsB | hiddenB | W1t | W2t | protoC | p2 | idx
// ---------------------------------------------------------------------------
extern "C" void kernel_launch(void* const* d_in, const int* in_sizes, int n_in,
                              void* d_out, int out_size, void* d_ws, size_t ws_size,
                              hipStream_t stream) {
  const float* feats  = (const float*)d_in[0];
  const float* protos = (const float*)d_in[1];
  const float* W1     = (const float*)d_in[2];
  const float* b1     = (const float*)d_in[3];
  const float* W2     = (const float*)d_in[4];
  const float* b2     = (const float*)d_in[5];
  float* out = (float*)d_out;

  unsigned short* featsB  = (unsigned short*)d_ws;
  unsigned short* hiddenB = featsB + (size_t)BATCH * HDIM;
  unsigned short* W1t     = hiddenB + (size_t)BATCH * HDIM;   // top half only
  unsigned short* W2t     = W1t + (size_t)HDIM * HDIM;
  float* protoC = (float*)(W2t + (size_t)HDIM * HDIM);        // [NFAM][HDIM]
  float* p2     = protoC + NFAM * HDIM;
  int* idx      = (int*)(p2 + NFAM + 2);

  // W1 top half [1024][1024] -> bf16 [n][k]; W2 [1024][1024] -> bf16 [n][k]
  transpose_cast<<<dim3(HDIM / 64, HDIM / 64), 256, 0, stream>>>(W1, W1t, HDIM, HDIM);
  transpose_cast<<<dim3(HDIM / 64, HDIM / 64), 256, 0, stream>>>(W2, W2t, HDIM, HDIM);
  proto_prep<<<NFAM, 256, 0, stream>>>(protos, p2);
  proto_contrib<<<dim3(HDIM / 64, NFAM), 256, 0, stream>>>(protos, W1, b1, protoC);
  nearest_kernel<<<BATCH / 16, 256, 0, stream>>>(feats, protos, p2, featsB, idx);
  // GEMM1: hidden = relu(feats @ W1top + protoC[idx])     K=1024
  gemm_kernel<1><<<2048, 256, 0, stream>>>(featsB, W1t, idx, protoC, nullptr, hiddenB, nullptr);
  // GEMM2: out = hidden @ W2 + b2                          K=1024
  gemm_kernel<0><<<2048, 256, 0, stream>>>(hiddenB, W2t, nullptr, nullptr, b2, nullptr, out);
}